// Round 1
// baseline (451.033 us; speedup 1.0000x reference)
//
#include <hip/hip_runtime.h>
#include <stdint.h>

typedef __attribute__((ext_vector_type(8))) short short8;
typedef __attribute__((ext_vector_type(4))) float f32x4;
typedef __attribute__((ext_vector_type(4))) unsigned short us4;

#define B_ 4
#define S_ 2048
#define D_ 1024
#define H_ 16
#define DK_ 64

__device__ __forceinline__ unsigned short f2bf(float f) {
  union { float f; unsigned int u; } c; c.f = f;
  unsigned int r = (c.u + 0x7fffu + ((c.u >> 16) & 1u)) >> 16;
  return (unsigned short)r;
}

__device__ __forceinline__ void glds16(const void* g, void* l) {
  __builtin_amdgcn_global_load_lds(
      (__attribute__((address_space(1))) void*)(uintptr_t)g,
      (__attribute__((address_space(3))) void*)l, 16, 0, 0);
}

__device__ __forceinline__ f32x4 mfma_bf16(short8 a, short8 b, f32x4 c) {
  return __builtin_amdgcn_mfma_f32_16x16x32_bf16(a, b, c, 0, 0, 0);
}

// ---------------- LayerNorm (fp32 in) -> bf16 out, one wave per row ----------------
__global__ __launch_bounds__(256) void ln_bf16(const float* __restrict__ x,
                                               const float* __restrict__ g,
                                               const float* __restrict__ bta,
                                               unsigned short* __restrict__ y) {
  const int lane = threadIdx.x & 63, wid = threadIdx.x >> 6;
  const int row = blockIdx.x * 4 + wid;
  const float4* xr = (const float4*)(x + (size_t)row * D_);
  float4 v[4];
  float s1 = 0.f, s2 = 0.f;
#pragma unroll
  for (int i = 0; i < 4; ++i) {
    v[i] = xr[i * 64 + lane];
    s1 += v[i].x + v[i].y + v[i].z + v[i].w;
    s2 += v[i].x * v[i].x + v[i].y * v[i].y + v[i].z * v[i].z + v[i].w * v[i].w;
  }
#pragma unroll
  for (int m = 32; m; m >>= 1) { s1 += __shfl_xor(s1, m); s2 += __shfl_xor(s2, m); }
  const float mu = s1 * (1.f / D_);
  const float inv = rsqrtf(s2 * (1.f / D_) - mu * mu + 1e-5f);
  const float4* gp = (const float4*)g;
  const float4* bp = (const float4*)bta;
  us4* yr = (us4*)(y + (size_t)row * D_);
#pragma unroll
  for (int i = 0; i < 4; ++i) {
    float4 gv = gp[i * 64 + lane], bv = bp[i * 64 + lane];
    us4 o;
    o[0] = f2bf((v[i].x - mu) * inv * gv.x + bv.x);
    o[1] = f2bf((v[i].y - mu) * inv * gv.y + bv.y);
    o[2] = f2bf((v[i].z - mu) * inv * gv.z + bv.z);
    o[3] = f2bf((v[i].w - mu) * inv * gv.w + bv.w);
    yr[i * 64 + lane] = o;
  }
}

// ---------------- Weight transpose fp32 [K][N] -> bf16 Wt [N][K] ----------------
__global__ void wt_bf16(const float* __restrict__ W, unsigned short* __restrict__ Wt) {
  __shared__ float t[32][33];
  const int n0 = blockIdx.x * 32, k0 = blockIdx.y * 32;
  const int tx = threadIdx.x, ty = threadIdx.y;  // (32,8)
  for (int i = ty; i < 32; i += 8) t[i][tx] = W[(size_t)(k0 + i) * D_ + n0 + tx];
  __syncthreads();
  for (int i = ty; i < 32; i += 8)
    Wt[(size_t)(n0 + i) * D_ + k0 + tx] = f2bf(t[tx][i]);
}

// ---------------- V transpose: [BH][S][dk] -> [BH][dk][S] (bf16) ----------------
__global__ void vt_k(const unsigned short* __restrict__ Vh, unsigned short* __restrict__ Vt) {
  __shared__ unsigned short t[64][65];
  const int s0 = blockIdx.x * 64, bh = blockIdx.y;
  const int tx = threadIdx.x, ty = threadIdx.y;  // (64,4)
  const unsigned short* src = Vh + (size_t)bh * S_ * DK_;
  unsigned short* dst = Vt + (size_t)bh * DK_ * S_;
  for (int i = ty; i < 64; i += 4) t[i][tx] = src[(size_t)(s0 + i) * DK_ + tx];
  __syncthreads();
  for (int i = ty; i < 64; i += 4) dst[(size_t)i * S_ + s0 + tx] = t[tx][i];
}

// ---------------- GEMM: C[8192,1024] = A[8192,1024] @ Bt^T, m97 structure ----------------
// MODE 0: out bf16 scattered to [B,H,S,dk] with scale
// MODE 1: out fp32 row-major + residual
template <int MODE>
__global__ __launch_bounds__(256, 2) void gemm_bt(const unsigned short* __restrict__ A,
                                                  const unsigned short* __restrict__ Bt,
                                                  void* __restrict__ outp, float scale,
                                                  const float* __restrict__ resid) {
  constexpr int K = D_;
  __shared__ __attribute__((aligned(16))) unsigned short As[128][64];
  __shared__ __attribute__((aligned(16))) unsigned short Bs[128][64];
  const int tid = threadIdx.x;
  const int lane = tid & 63, wid = tid >> 6;
  const int lo16 = lane & 15, hi4 = lane >> 4;
  const int wr = wid >> 1, wc = wid & 1;
  const int mbase = blockIdx.y * 128, nbase = blockIdx.x * 128;
  const int srow = lane >> 3, scol = (lane & 7) * 8;

  f32x4 acc[4][4] = {};

  for (int kt = 0; kt < K / 64; ++kt) {
    __syncthreads();
    const int kb = kt * 64;
#pragma unroll
    for (int c = 0; c < 4; ++c) {
      const int ch = wid * 4 + c;  // 0..15
      glds16(A + (size_t)(mbase + ch * 8 + srow) * K + kb + scol,
             (unsigned short*)As + ch * 512);
      glds16(Bt + (size_t)(nbase + ch * 8 + srow) * K + kb + scol,
             (unsigned short*)Bs + ch * 512);
    }
    __syncthreads();
#pragma unroll
    for (int kk = 0; kk < 2; ++kk) {
      short8 af[4], bfr[4];
#pragma unroll
      for (int i = 0; i < 4; ++i)
        af[i] = *(const short8*)&As[wr * 64 + i * 16 + lo16][kk * 32 + hi4 * 8];
#pragma unroll
      for (int j = 0; j < 4; ++j)
        bfr[j] = *(const short8*)&Bs[wc * 64 + j * 16 + lo16][kk * 32 + hi4 * 8];
#pragma unroll
      for (int i = 0; i < 4; ++i)
#pragma unroll
        for (int j = 0; j < 4; ++j) acc[i][j] = mfma_bf16(af[i], bfr[j], acc[i][j]);
    }
  }

  if (MODE == 0) {
    unsigned short* out = (unsigned short*)outp;
#pragma unroll
    for (int i = 0; i < 4; ++i) {
      const int row = mbase + wr * 64 + i * 16 + hi4 * 4;
      const int b = row >> 11, s = row & (S_ - 1);
#pragma unroll
      for (int j = 0; j < 4; ++j) {
        const int col = nbase + wc * 64 + j * 16 + lo16;
        const int h = col >> 6, d = col & 63;
        const size_t base = ((size_t)(b * H_ + h) * S_ + s) * DK_ + d;
#pragma unroll
        for (int r = 0; r < 4; ++r) out[base + (size_t)r * DK_] = f2bf(acc[i][j][r] * scale);
      }
    }
  } else {
    float* out = (float*)outp;
#pragma unroll
    for (int i = 0; i < 4; ++i) {
      const int row = mbase + wr * 64 + i * 16 + hi4 * 4;
#pragma unroll
      for (int j = 0; j < 4; ++j) {
        const int col = nbase + wc * 64 + j * 16 + lo16;
        const size_t idx = (size_t)row * D_ + col;
#pragma unroll
        for (int r = 0; r < 4; ++r)
          out[idx + (size_t)r * D_] = acc[i][j][r] + resid[idx + (size_t)r * D_];
      }
    }
  }
}

// ---------------- Flash attention: 128 q-rows/block, 64-wide K/V tiles ----------------
__global__ __launch_bounds__(256, 2) void attn_k(const unsigned short* __restrict__ Qh,
                                                 const unsigned short* __restrict__ Kh,
                                                 const unsigned short* __restrict__ Vt,
                                                 const int* __restrict__ mask,
                                                 unsigned short* __restrict__ O) {
  __shared__ __attribute__((aligned(16))) unsigned short Ks[64][64];
  __shared__ __attribute__((aligned(16))) unsigned short Vs[64][64];  // [d][krow]
  __shared__ __attribute__((aligned(16))) unsigned short Ps[128][64];
  const int tid = threadIdx.x, lane = tid & 63, wid = tid >> 6;
  const int lo16 = lane & 15, hi4 = lane >> 4;
  const int qb = blockIdx.x, bh = blockIdx.y, b = bh >> 4, h = bh & 15;
  const unsigned short* Qb = Qh + (size_t)bh * S_ * DK_;
  const unsigned short* Kb = Kh + (size_t)bh * S_ * DK_;
  const unsigned short* Vb = Vt + (size_t)bh * DK_ * S_;
  const int* mb = mask + b * S_;
  const int srow = lane >> 3, scol = (lane & 7) * 8;

  short8 qf[2][2];
#pragma unroll
  for (int i = 0; i < 2; ++i)
#pragma unroll
    for (int kk = 0; kk < 2; ++kk)
      qf[i][kk] = *(const short8*)(Qb + (size_t)(qb * 128 + wid * 32 + i * 16 + lo16) * DK_ +
                                   kk * 32 + hi4 * 8);

  f32x4 o[2][4] = {};
  float mreg[2][4], lreg[2][4];
#pragma unroll
  for (int i = 0; i < 2; ++i)
#pragma unroll
    for (int r = 0; r < 4; ++r) { mreg[i][r] = -1e30f; lreg[i][r] = 0.f; }

  for (int kt = 0; kt < S_ / 64; ++kt) {
    __syncthreads();
#pragma unroll
    for (int c = 0; c < 2; ++c) {
      const int ch = wid * 2 + c;  // 0..7
      glds16(Kb + (size_t)(kt * 64 + ch * 8 + srow) * DK_ + scol,
             (unsigned short*)Ks + ch * 512);
      glds16(Vb + (size_t)(ch * 8 + srow) * S_ + kt * 64 + scol,
             (unsigned short*)Vs + ch * 512);
    }
    __syncthreads();

    f32x4 s[2][4] = {};
#pragma unroll
    for (int kk = 0; kk < 2; ++kk)
#pragma unroll
      for (int nf = 0; nf < 4; ++nf) {
        short8 kf = *(const short8*)&Ks[nf * 16 + lo16][kk * 32 + hi4 * 8];
#pragma unroll
        for (int i = 0; i < 2; ++i) s[i][nf] = mfma_bf16(qf[i][kk], kf, s[i][nf]);
      }
    // mask (key mask, col = kt*64 + nf*16 + lo16)
#pragma unroll
    for (int nf = 0; nf < 4; ++nf) {
      if (mb[kt * 64 + nf * 16 + lo16] == 0) {
#pragma unroll
        for (int i = 0; i < 2; ++i) {
          s[i][nf][0] = -1e30f; s[i][nf][1] = -1e30f; s[i][nf][2] = -1e30f; s[i][nf][3] = -1e30f;
        }
      }
    }
    // online softmax
#pragma unroll
    for (int i = 0; i < 2; ++i) {
#pragma unroll
      for (int r = 0; r < 4; ++r) {
        float cur = fmaxf(fmaxf(s[i][0][r], s[i][1][r]), fmaxf(s[i][2][r], s[i][3][r]));
        cur = fmaxf(cur, __shfl_xor(cur, 1));
        cur = fmaxf(cur, __shfl_xor(cur, 2));
        cur = fmaxf(cur, __shfl_xor(cur, 4));
        cur = fmaxf(cur, __shfl_xor(cur, 8));
        const float mnew = fmaxf(mreg[i][r], cur);
        const float fac = __expf(mreg[i][r] - mnew);
        mreg[i][r] = mnew;
        float psum = 0.f;
#pragma unroll
        for (int nf = 0; nf < 4; ++nf) {
          float p = __expf(s[i][nf][r] - mnew);
          s[i][nf][r] = p;
          psum += p;
        }
        psum += __shfl_xor(psum, 1);
        psum += __shfl_xor(psum, 2);
        psum += __shfl_xor(psum, 4);
        psum += __shfl_xor(psum, 8);
        lreg[i][r] = lreg[i][r] * fac + psum;
#pragma unroll
        for (int df = 0; df < 4; ++df) o[i][df][r] *= fac;
      }
    }
    // P -> LDS (bf16)
#pragma unroll
    for (int i = 0; i < 2; ++i)
#pragma unroll
      for (int nf = 0; nf < 4; ++nf)
#pragma unroll
        for (int r = 0; r < 4; ++r)
          Ps[wid * 32 + i * 16 + hi4 * 4 + r][nf * 16 + lo16] = f2bf(s[i][nf][r]);
    __syncthreads();
    // PV
#pragma unroll
    for (int kk = 0; kk < 2; ++kk) {
      short8 pa0 = *(const short8*)&Ps[wid * 32 + 0 + lo16][kk * 32 + hi4 * 8];
      short8 pa1 = *(const short8*)&Ps[wid * 32 + 16 + lo16][kk * 32 + hi4 * 8];
#pragma unroll
      for (int df = 0; df < 4; ++df) {
        short8 vf = *(const short8*)&Vs[df * 16 + lo16][kk * 32 + hi4 * 8];
        o[0][df] = mfma_bf16(pa0, vf, o[0][df]);
        o[1][df] = mfma_bf16(pa1, vf, o[1][df]);
      }
    }
  }
  // normalize + store O [B][S][D] with col = h*64+d
#pragma unroll
  for (int i = 0; i < 2; ++i) {
#pragma unroll
    for (int r = 0; r < 4; ++r) {
      const int srowg = qb * 128 + wid * 32 + i * 16 + hi4 * 4 + r;
      const float rl = lreg[i][r] > 0.f ? 1.f / lreg[i][r] : 0.f;
      const size_t base = ((size_t)b * S_ + srowg) * D_ + h * 64;
#pragma unroll
      for (int df = 0; df < 4; ++df) O[base + df * 16 + lo16] = f2bf(o[i][df][r] * rl);
    }
  }
}

extern "C" void kernel_launch(void* const* d_in, const int* in_sizes, int n_in,
                              void* d_out, int out_size, void* d_ws, size_t ws_size,
                              hipStream_t stream) {
  const float* q = (const float*)d_in[0];
  const float* k = (const float*)d_in[1];
  const float* v = (const float*)d_in[2];
  const int* mask = (const int*)d_in[3];
  const float* Wq = (const float*)d_in[4];
  const float* Wk = (const float*)d_in[5];
  const float* Wv = (const float*)d_in[6];
  const float* Wo = (const float*)d_in[7];
  const float* lnqg = (const float*)d_in[8];
  const float* lnqb = (const float*)d_in[9];
  const float* lnkg = (const float*)d_in[10];
  const float* lnkb = (const float*)d_in[11];
  const float* lnvg = (const float*)d_in[12];
  const float* lnvb = (const float*)d_in[13];

  uint8_t* ws = (uint8_t*)d_ws;
  const size_t MB = 1024ull * 1024ull;
  unsigned short* Xq = (unsigned short*)(ws + 0 * MB);
  unsigned short* Xk = (unsigned short*)(ws + 16 * MB);
  unsigned short* Xv = (unsigned short*)(ws + 32 * MB);
  unsigned short* Wqt = (unsigned short*)(ws + 48 * MB);
  unsigned short* Wkt = (unsigned short*)(ws + 50 * MB);
  unsigned short* Wvt = (unsigned short*)(ws + 52 * MB);
  unsigned short* Wot = (unsigned short*)(ws + 54 * MB);
  unsigned short* Qh = (unsigned short*)(ws + 56 * MB);
  unsigned short* Kh = (unsigned short*)(ws + 72 * MB);
  unsigned short* Vh = Xq;   // reuse: Xq dead after Q-GEMM
  unsigned short* Vtb = Xk;  // reuse: Xk dead after K-GEMM
  unsigned short* Ob = Xv;   // reuse: Xv dead after V-GEMM

  dim3 wtb(32, 8);
  hipLaunchKernelGGL(wt_bf16, dim3(32, 32), wtb, 0, stream, Wq, Wqt);
  hipLaunchKernelGGL(wt_bf16, dim3(32, 32), wtb, 0, stream, Wk, Wkt);
  hipLaunchKernelGGL(wt_bf16, dim3(32, 32), wtb, 0, stream, Wv, Wvt);
  hipLaunchKernelGGL(wt_bf16, dim3(32, 32), wtb, 0, stream, Wo, Wot);

  hipLaunchKernelGGL(ln_bf16, dim3(2048), dim3(256), 0, stream, q, lnqg, lnqb, Xq);
  hipLaunchKernelGGL(ln_bf16, dim3(2048), dim3(256), 0, stream, k, lnkg, lnkb, Xk);
  hipLaunchKernelGGL(ln_bf16, dim3(2048), dim3(256), 0, stream, v, lnvg, lnvb, Xv);

  dim3 gg(D_ / 128, (B_ * S_) / 128);
  hipLaunchKernelGGL(gemm_bt<0>, gg, dim3(256), 0, stream, Xq, Wqt, (void*)Qh, 0.125f, (const float*)nullptr);
  hipLaunchKernelGGL(gemm_bt<0>, gg, dim3(256), 0, stream, Xk, Wkt, (void*)Kh, 1.0f, (const float*)nullptr);
  hipLaunchKernelGGL(gemm_bt<0>, gg, dim3(256), 0, stream, Xv, Wvt, (void*)Vh, 1.0f, (const float*)nullptr);

  hipLaunchKernelGGL(vt_k, dim3(S_ / 64, B_ * H_), dim3(64, 4), 0, stream, Vh, Vtb);

  hipLaunchKernelGGL(attn_k, dim3(S_ / 128, B_ * H_), dim3(256), 0, stream, Qh, Kh, Vtb, mask, Ob);

  hipLaunchKernelGGL(gemm_bt<1>, gg, dim3(256), 0, stream, Ob, Wot, d_out, 1.0f, q);
}

// Round 2
// 377.721 us; speedup vs baseline: 1.1941x; 1.1941x over previous
//
#include <hip/hip_runtime.h>
#include <stdint.h>

typedef __attribute__((ext_vector_type(8))) short short8;
typedef __attribute__((ext_vector_type(4))) float f32x4;
typedef __attribute__((ext_vector_type(4))) unsigned short us4;

#define B_ 4
#define S_ 2048
#define D_ 1024
#define H_ 16
#define DK_ 64

__device__ __forceinline__ unsigned short f2bf(float f) {
  union { float f; unsigned int u; } c; c.f = f;
  unsigned int r = (c.u + 0x7fffu + ((c.u >> 16) & 1u)) >> 16;
  return (unsigned short)r;
}

__device__ __forceinline__ void glds16(const void* g, void* l) {
  __builtin_amdgcn_global_load_lds(
      (__attribute__((address_space(1))) void*)(uintptr_t)g,
      (__attribute__((address_space(3))) void*)l, 16, 0, 0);
}

__device__ __forceinline__ f32x4 mfma_bf16(short8 a, short8 b, f32x4 c) {
  return __builtin_amdgcn_mfma_f32_16x16x32_bf16(a, b, c, 0, 0, 0);
}

// ---------------- LayerNorm (fp32 in) -> bf16 out, one wave per row ----------------
__global__ __launch_bounds__(256) void ln_bf16(const float* __restrict__ x,
                                               const float* __restrict__ g,
                                               const float* __restrict__ bta,
                                               unsigned short* __restrict__ y) {
  const int lane = threadIdx.x & 63, wid = threadIdx.x >> 6;
  const int row = blockIdx.x * 4 + wid;
  const float4* xr = (const float4*)(x + (size_t)row * D_);
  float4 v[4];
  float s1 = 0.f, s2 = 0.f;
#pragma unroll
  for (int i = 0; i < 4; ++i) {
    v[i] = xr[i * 64 + lane];
    s1 += v[i].x + v[i].y + v[i].z + v[i].w;
    s2 += v[i].x * v[i].x + v[i].y * v[i].y + v[i].z * v[i].z + v[i].w * v[i].w;
  }
#pragma unroll
  for (int m = 32; m; m >>= 1) { s1 += __shfl_xor(s1, m); s2 += __shfl_xor(s2, m); }
  const float mu = s1 * (1.f / D_);
  const float inv = rsqrtf(s2 * (1.f / D_) - mu * mu + 1e-5f);
  const float4* gp = (const float4*)g;
  const float4* bp = (const float4*)bta;
  us4* yr = (us4*)(y + (size_t)row * D_);
#pragma unroll
  for (int i = 0; i < 4; ++i) {
    float4 gv = gp[i * 64 + lane], bv = bp[i * 64 + lane];
    us4 o;
    o[0] = f2bf((v[i].x - mu) * inv * gv.x + bv.x);
    o[1] = f2bf((v[i].y - mu) * inv * gv.y + bv.y);
    o[2] = f2bf((v[i].z - mu) * inv * gv.z + bv.z);
    o[3] = f2bf((v[i].w - mu) * inv * gv.w + bv.w);
    yr[i * 64 + lane] = o;
  }
}

// ---------------- Weight transpose fp32 [K][N] -> bf16 Wt [N][K] ----------------
__global__ void wt_bf16(const float* __restrict__ W, unsigned short* __restrict__ Wt) {
  __shared__ float t[32][33];
  const int n0 = blockIdx.x * 32, k0 = blockIdx.y * 32;
  const int tx = threadIdx.x, ty = threadIdx.y;  // (32,8)
  for (int i = ty; i < 32; i += 8) t[i][tx] = W[(size_t)(k0 + i) * D_ + n0 + tx];
  __syncthreads();
  for (int i = ty; i < 32; i += 8)
    Wt[(size_t)(n0 + i) * D_ + k0 + tx] = f2bf(t[tx][i]);
}

// ---------------- V transpose: [BH][S][dk] -> [BH][dk][S] (bf16) ----------------
__global__ void vt_k(const unsigned short* __restrict__ Vh, unsigned short* __restrict__ Vt) {
  __shared__ unsigned short t[64][65];
  const int s0 = blockIdx.x * 64, bh = blockIdx.y;
  const int tx = threadIdx.x, ty = threadIdx.y;  // (64,4)
  const unsigned short* src = Vh + (size_t)bh * S_ * DK_;
  unsigned short* dst = Vt + (size_t)bh * DK_ * S_;
  for (int i = ty; i < 64; i += 4) t[i][tx] = src[(size_t)(s0 + i) * DK_ + tx];
  __syncthreads();
  for (int i = ty; i < 64; i += 4) dst[(size_t)i * S_ + s0 + tx] = t[tx][i];
}

// ---------------- GEMM: C[8192,1024] = A[8192,1024] @ Bt^T, m97 structure ----------------
template <int MODE>
__global__ __launch_bounds__(256, 2) void gemm_bt(const unsigned short* __restrict__ A,
                                                  const unsigned short* __restrict__ Bt,
                                                  void* __restrict__ outp, float scale,
                                                  const float* __restrict__ resid) {
  constexpr int K = D_;
  __shared__ __attribute__((aligned(16))) unsigned short As[128][64];
  __shared__ __attribute__((aligned(16))) unsigned short Bs[128][64];
  const int tid = threadIdx.x;
  const int lane = tid & 63, wid = tid >> 6;
  const int lo16 = lane & 15, hi4 = lane >> 4;
  const int wr = wid >> 1, wc = wid & 1;
  const int mbase = blockIdx.y * 128, nbase = blockIdx.x * 128;
  const int srow = lane >> 3, scol = (lane & 7) * 8;

  f32x4 acc[4][4] = {};

  for (int kt = 0; kt < K / 64; ++kt) {
    __syncthreads();
    const int kb = kt * 64;
#pragma unroll
    for (int c = 0; c < 4; ++c) {
      const int ch = wid * 4 + c;  // 0..15
      glds16(A + (size_t)(mbase + ch * 8 + srow) * K + kb + scol,
             (unsigned short*)As + ch * 512);
      glds16(Bt + (size_t)(nbase + ch * 8 + srow) * K + kb + scol,
             (unsigned short*)Bs + ch * 512);
    }
    __syncthreads();
#pragma unroll
    for (int kk = 0; kk < 2; ++kk) {
      short8 af[4], bfr[4];
#pragma unroll
      for (int i = 0; i < 4; ++i)
        af[i] = *(const short8*)&As[wr * 64 + i * 16 + lo16][kk * 32 + hi4 * 8];
#pragma unroll
      for (int j = 0; j < 4; ++j)
        bfr[j] = *(const short8*)&Bs[wc * 64 + j * 16 + lo16][kk * 32 + hi4 * 8];
#pragma unroll
      for (int i = 0; i < 4; ++i)
#pragma unroll
        for (int j = 0; j < 4; ++j) acc[i][j] = mfma_bf16(af[i], bfr[j], acc[i][j]);
    }
  }

  if (MODE == 0) {
    unsigned short* out = (unsigned short*)outp;
#pragma unroll
    for (int i = 0; i < 4; ++i) {
      const int row = mbase + wr * 64 + i * 16 + hi4 * 4;
      const int b = row >> 11, s = row & (S_ - 1);
#pragma unroll
      for (int j = 0; j < 4; ++j) {
        const int col = nbase + wc * 64 + j * 16 + lo16;
        const int h = col >> 6, d = col & 63;
        const size_t base = ((size_t)(b * H_ + h) * S_ + s) * DK_ + d;
#pragma unroll
        for (int r = 0; r < 4; ++r) out[base + (size_t)r * DK_] = f2bf(acc[i][j][r] * scale);
      }
    }
  } else {
    float* out = (float*)outp;
#pragma unroll
    for (int i = 0; i < 4; ++i) {
      const int row = mbase + wr * 64 + i * 16 + hi4 * 4;
#pragma unroll
      for (int j = 0; j < 4; ++j) {
        const int col = nbase + wc * 64 + j * 16 + lo16;
        const size_t idx = (size_t)row * D_ + col;
#pragma unroll
        for (int r = 0; r < 4; ++r)
          out[idx + (size_t)r * D_] = acc[i][j][r] + resid[idx + (size_t)r * D_];
      }
    }
  }
}

// ---------------- Flash attention: 128 q-rows/block, 64-wide K/V tiles ----------------
// Round-1 changes: XOR-swizzled K/V/P LDS (kills 16-way bank conflicts),
// double-buffered K/V with prefetch across a raw mid-barrier (no vmcnt drain),
// mask staged to LDS (keeps vmcnt chain clean), setprio around MFMA, 3 blocks/CU.
__global__ __launch_bounds__(256, 3) void attn_k(const unsigned short* __restrict__ Qh,
                                                 const unsigned short* __restrict__ Kh,
                                                 const unsigned short* __restrict__ Vt,
                                                 const int* __restrict__ mask,
                                                 unsigned short* __restrict__ O) {
  __shared__ __attribute__((aligned(16))) unsigned short Ks[2][64][64];
  __shared__ __attribute__((aligned(16))) unsigned short Vs[2][64][64];  // [d][krow]
  __shared__ __attribute__((aligned(16))) unsigned short Ps[128][64];
  __shared__ unsigned short MskL[S_];
  const int tid = threadIdx.x, lane = tid & 63, wid = tid >> 6;
  const int lo16 = lane & 15, hi4 = lane >> 4;
  const int swz = (lo16 & 7) << 3;  // read-side XOR (ushort units, 16B blocks)
  const int qb = blockIdx.x, bh = blockIdx.y, b = bh >> 4, h = bh & 15;
  const unsigned short* Qb = Qh + (size_t)bh * S_ * DK_;
  const unsigned short* Kb = Kh + (size_t)bh * S_ * DK_;
  const unsigned short* Vb = Vt + (size_t)bh * DK_ * S_;
  const int* mb = mask + b * S_;
  const int srow = lane >> 3;
  const int scolx = ((lane & 7) ^ srow) * 8;  // source-side inverse swizzle (involution)

  // stage mask flags to LDS once (ds reads later; no vmcnt pollution mid-loop)
  for (int t = tid; t < S_; t += 256) MskL[t] = (unsigned short)(mb[t] != 0);

  short8 qf[2][2];
#pragma unroll
  for (int i = 0; i < 2; ++i)
#pragma unroll
    for (int kk = 0; kk < 2; ++kk)
      qf[i][kk] = *(const short8*)(Qb + (size_t)(qb * 128 + wid * 32 + i * 16 + lo16) * DK_ +
                                   kk * 32 + hi4 * 8);

  f32x4 o[2][4] = {};
  float mreg[2][4], lreg[2][4];
#pragma unroll
  for (int i = 0; i < 2; ++i)
#pragma unroll
    for (int r = 0; r < 4; ++r) { mreg[i][r] = -1e30f; lreg[i][r] = 0.f; }

  // stage K/V tile kt into buffer bufi (linear LDS dest, pre-swizzled global source)
  auto stageKV = [&](int bufi, int kt) {
#pragma unroll
    for (int c = 0; c < 2; ++c) {
      const int ch = wid * 2 + c;  // 0..7
      glds16(Kb + (size_t)(kt * 64 + ch * 8 + srow) * DK_ + scolx,
             (unsigned short*)&Ks[bufi][0][0] + ch * 512);
      glds16(Vb + (size_t)(ch * 8 + srow) * S_ + kt * 64 + scolx,
             (unsigned short*)&Vs[bufi][0][0] + ch * 512);
    }
  };

  stageKV(0, 0);
  int cur = 0;

  for (int kt = 0; kt < S_ / 64; ++kt) {
    __syncthreads();  // buf[cur] staged (vmcnt drained), prev PV reads done
    if (kt + 1 < S_ / 64) stageKV(cur ^ 1, kt + 1);  // prefetch stays in flight

    const unsigned short* Kc = &Ks[cur][0][0];
    f32x4 s[2][4] = {};
    __builtin_amdgcn_s_setprio(1);
#pragma unroll
    for (int kk = 0; kk < 2; ++kk)
#pragma unroll
      for (int nf = 0; nf < 4; ++nf) {
        short8 kf = *(const short8*)(Kc + (nf * 16 + lo16) * 64 + ((kk * 32 + hi4 * 8) ^ swz));
#pragma unroll
        for (int i = 0; i < 2; ++i) s[i][nf] = mfma_bf16(qf[i][kk], kf, s[i][nf]);
      }
    __builtin_amdgcn_s_setprio(0);
    // mask (key mask, col = kt*64 + nf*16 + lo16), from LDS
#pragma unroll
    for (int nf = 0; nf < 4; ++nf) {
      if (MskL[kt * 64 + nf * 16 + lo16] == 0) {
#pragma unroll
        for (int i = 0; i < 2; ++i) {
          s[i][nf][0] = -1e30f; s[i][nf][1] = -1e30f; s[i][nf][2] = -1e30f; s[i][nf][3] = -1e30f;
        }
      }
    }
    // online softmax (row = wid*32+i*16+hi4*4+r, cols across nf & lo16 lanes)
#pragma unroll
    for (int i = 0; i < 2; ++i) {
#pragma unroll
      for (int r = 0; r < 4; ++r) {
        float cur_m = fmaxf(fmaxf(s[i][0][r], s[i][1][r]), fmaxf(s[i][2][r], s[i][3][r]));
        cur_m = fmaxf(cur_m, __shfl_xor(cur_m, 1));
        cur_m = fmaxf(cur_m, __shfl_xor(cur_m, 2));
        cur_m = fmaxf(cur_m, __shfl_xor(cur_m, 4));
        cur_m = fmaxf(cur_m, __shfl_xor(cur_m, 8));
        const float mnew = fmaxf(mreg[i][r], cur_m);
        const float fac = __expf(mreg[i][r] - mnew);
        mreg[i][r] = mnew;
        float psum = 0.f;
#pragma unroll
        for (int nf = 0; nf < 4; ++nf) {
          float p = __expf(s[i][nf][r] - mnew);
          s[i][nf][r] = p;
          psum += p;
        }
        psum += __shfl_xor(psum, 1);
        psum += __shfl_xor(psum, 2);
        psum += __shfl_xor(psum, 4);
        psum += __shfl_xor(psum, 8);
        lreg[i][r] = lreg[i][r] * fac + psum;
#pragma unroll
        for (int df = 0; df < 4; ++df) o[i][df][r] *= fac;
      }
    }
    // P -> LDS (bf16), swizzled write
#pragma unroll
    for (int i = 0; i < 2; ++i)
#pragma unroll
      for (int nf = 0; nf < 4; ++nf)
#pragma unroll
        for (int r = 0; r < 4; ++r) {
          const int pr = wid * 32 + i * 16 + hi4 * 4 + r;
          Ps[pr][(nf * 16 + lo16) ^ ((pr & 7) << 3)] = f2bf(s[i][nf][r]);
        }
    // mid barrier: lgkmcnt(0) only — keep prefetch glds in flight (no vmcnt drain)
    asm volatile("s_waitcnt lgkmcnt(0)" ::: "memory");
    __builtin_amdgcn_s_barrier();
    // PV
    const unsigned short* Vc = &Vs[cur][0][0];
    __builtin_amdgcn_s_setprio(1);
#pragma unroll
    for (int kk = 0; kk < 2; ++kk) {
      const int pc = (kk * 32 + hi4 * 8) ^ swz;
      short8 pa0 = *(const short8*)((const unsigned short*)Ps + (wid * 32 + 0 + lo16) * 64 + pc);
      short8 pa1 = *(const short8*)((const unsigned short*)Ps + (wid * 32 + 16 + lo16) * 64 + pc);
#pragma unroll
      for (int df = 0; df < 4; ++df) {
        short8 vf = *(const short8*)(Vc + (df * 16 + lo16) * 64 + pc);
        o[0][df] = mfma_bf16(pa0, vf, o[0][df]);
        o[1][df] = mfma_bf16(pa1, vf, o[1][df]);
      }
    }
    __builtin_amdgcn_s_setprio(0);
    cur ^= 1;
  }
  // normalize + store O [B][S][D] with col = h*64+d
#pragma unroll
  for (int i = 0; i < 2; ++i) {
#pragma unroll
    for (int r = 0; r < 4; ++r) {
      const int srowg = qb * 128 + wid * 32 + i * 16 + hi4 * 4 + r;
      const float rl = lreg[i][r] > 0.f ? 1.f / lreg[i][r] : 0.f;
      const size_t base = ((size_t)b * S_ + srowg) * D_ + h * 64;
#pragma unroll
      for (int df = 0; df < 4; ++df) O[base + df * 16 + lo16] = f2bf(o[i][df][r] * rl);
    }
  }
}

extern "C" void kernel_launch(void* const* d_in, const int* in_sizes, int n_in,
                              void* d_out, int out_size, void* d_ws, size_t ws_size,
                              hipStream_t stream) {
  const float* q = (const float*)d_in[0];
  const float* k = (const float*)d_in[1];
  const float* v = (const float*)d_in[2];
  const int* mask = (const int*)d_in[3];
  const float* Wq = (const float*)d_in[4];
  const float* Wk = (const float*)d_in[5];
  const float* Wv = (const float*)d_in[6];
  const float* Wo = (const float*)d_in[7];
  const float* lnqg = (const float*)d_in[8];
  const float* lnqb = (const float*)d_in[9];
  const float* lnkg = (const float*)d_in[10];
  const float* lnkb = (const float*)d_in[11];
  const float* lnvg = (const float*)d_in[12];
  const float* lnvb = (const float*)d_in[13];

  uint8_t* ws = (uint8_t*)d_ws;
  const size_t MB = 1024ull * 1024ull;
  unsigned short* Xq = (unsigned short*)(ws + 0 * MB);
  unsigned short* Xk = (unsigned short*)(ws + 16 * MB);
  unsigned short* Xv = (unsigned short*)(ws + 32 * MB);
  unsigned short* Wqt = (unsigned short*)(ws + 48 * MB);
  unsigned short* Wkt = (unsigned short*)(ws + 50 * MB);
  unsigned short* Wvt = (unsigned short*)(ws + 52 * MB);
  unsigned short* Wot = (unsigned short*)(ws + 54 * MB);
  unsigned short* Qh = (unsigned short*)(ws + 56 * MB);
  unsigned short* Kh = (unsigned short*)(ws + 72 * MB);
  unsigned short* Vh = Xq;   // reuse: Xq dead after Q-GEMM
  unsigned short* Vtb = Xk;  // reuse: Xk dead after K-GEMM
  unsigned short* Ob = Xv;   // reuse: Xv dead after V-GEMM

  dim3 wtb(32, 8);
  hipLaunchKernelGGL(wt_bf16, dim3(32, 32), wtb, 0, stream, Wq, Wqt);
  hipLaunchKernelGGL(wt_bf16, dim3(32, 32), wtb, 0, stream, Wk, Wkt);
  hipLaunchKernelGGL(wt_bf16, dim3(32, 32), wtb, 0, stream, Wv, Wvt);
  hipLaunchKernelGGL(wt_bf16, dim3(32, 32), wtb, 0, stream, Wo, Wot);

  hipLaunchKernelGGL(ln_bf16, dim3(2048), dim3(256), 0, stream, q, lnqg, lnqb, Xq);
  hipLaunchKernelGGL(ln_bf16, dim3(2048), dim3(256), 0, stream, k, lnkg, lnkb, Xk);
  hipLaunchKernelGGL(ln_bf16, dim3(2048), dim3(256), 0, stream, v, lnvg, lnvb, Xv);

  dim3 gg(D_ / 128, (B_ * S_) / 128);
  hipLaunchKernelGGL(gemm_bt<0>, gg, dim3(256), 0, stream, Xq, Wqt, (void*)Qh, 0.125f, (const float*)nullptr);
  hipLaunchKernelGGL(gemm_bt<0>, gg, dim3(256), 0, stream, Xk, Wkt, (void*)Kh, 1.0f, (const float*)nullptr);
  hipLaunchKernelGGL(gemm_bt<0>, gg, dim3(256), 0, stream, Xv, Wvt, (void*)Vh, 1.0f, (const float*)nullptr);

  hipLaunchKernelGGL(vt_k, dim3(S_ / 64, B_ * H_), dim3(64, 4), 0, stream, Vh, Vtb);

  hipLaunchKernelGGL(attn_k, dim3(S_ / 128, B_ * H_), dim3(256), 0, stream, Qh, Kh, Vtb, mask, Ob);

  hipLaunchKernelGGL(gemm_bt<1>, gg, dim3(256), 0, stream, Ob, Wot, d_out, 1.0f, q);
}